// Round 8
// baseline (385.071 us; speedup 1.0000x reference)
//
#include <hip/hip_runtime.h>
#include <hip/hip_fp16.h>

#define N_NODES 50000
#define N_EDGES 1600000
#define DIM     128
#define NLAYERS 3
#define NGRAPHS 64

#define NBUCK   196            // buckets of 256 nodes: bucket = dst >> 8
#define CSR_BLKS 256
#define EPB     (N_EDGES / CSR_BLKS)   // 6250 edges per csr block
#define EITER   ((EPB + 255) / 256)    // 25

#define NSLICE  4              // feature slices for L2-resident gather
#define SLB     32             // bytes (fp8 cols) per slice
#define SLICE_BYTES ((size_t)N_NODES * SLB)   // 1.6 MB -- fits 4MB per-XCD L2

typedef _Float16 half8 __attribute__((ext_vector_type(8)));
typedef float    f32x4 __attribute__((ext_vector_type(4)));
typedef float    f32x2 __attribute__((ext_vector_type(2)));

#define LDK 136   // padded halves/row: 272B stride (16B-aligned), rotates banks

// ---------------------------------------------------------------- setup
// R23: X8 stored SLICE-MAJOR X8t[slice][node][32B] so each 32-col slice is
// a contiguous 1.6MB region (L2-resident gather source for agg).
__global__ __launch_bounds__(256) void setup_kernel(
        const float* __restrict__ X, __half* __restrict__ Xh,
        unsigned char* __restrict__ X8,
        const float* __restrict__ Wd, const float* __restrict__ Wc,
        const float* __restrict__ Ws, __half* __restrict__ WT,
        float* __restrict__ sums, int* __restrict__ gcnt) {
    int i = blockIdx.x * 256 + threadIdx.x;
    if (i < N_NODES * DIM / 4) {
        float4 v = *(const float4*)(X + (size_t)i * 4);
        union { __half2 h2[2]; uint2 u; } pk;
        pk.h2[0] = __floats2half2_rn(v.x, v.y);
        pk.h2[1] = __floats2half2_rn(v.z, v.w);
        *(uint2*)(Xh + (size_t)i * 4) = pk.u;
        int q0 = __builtin_amdgcn_cvt_pk_fp8_f32(v.x, v.y, 0, false);
        int q1 = __builtin_amdgcn_cvt_pk_fp8_f32(v.z, v.w, q0, true);
        int n  = i >> 5;                 // node (32 threads per node-row)
        int j0 = (i & 31) * 4;           // first col of this thread's 4
        int sl = j0 >> 5;                // slice
        int sb = j0 & 31;                // byte within slice
        *(unsigned int*)(X8 + sl * SLICE_BYTES + (size_t)n * SLB + sb) =
            (unsigned int)q1;
    }
    if (i < 9 * DIM * DIM) {   // WT[(l*3+w)][n][k] = W[l][k][n]
        int k  = i & 127;
        int n  = (i >> 7) & 127;
        int lw = i >> 14;
        int l  = lw / 3, w = lw - 3 * l;
        const float* W = ((w == 0) ? Wd : (w == 1) ? Wc : Ws)
                         + (size_t)l * DIM * DIM;
        WT[i] = __float2half(W[k * DIM + n]);
    }
    if (i < NGRAPHS * DIM) sums[i] = 0.f;
    if (i < NGRAPHS) gcnt[i] = 0;
}

// ---------------------------------------------------------------- CSR build
__global__ __launch_bounds__(256) void csr1_kernel(const int* __restrict__ dst,
                                                   int* __restrict__ cntmat) {
    __shared__ int hc[NBUCK];
    int tid = threadIdx.x;
    for (int i = tid; i < NBUCK; i += 256) hc[i] = 0;
    __syncthreads();
    int base = blockIdx.x * EPB;
#pragma unroll
    for (int i = 0; i < EITER; ++i) {
        int idx = i * 256 + tid;
        if (idx < EPB) atomicAdd(&hc[dst[base + idx] >> 8], 1);
    }
    __syncthreads();
    for (int i = tid; i < NBUCK; i += 256)
        cntmat[i * CSR_BLKS + blockIdx.x] = hc[i];
}

__global__ __launch_bounds__(256) void scanA_kernel(const int* __restrict__ cntmat,
                                                    int* __restrict__ exc,
                                                    int* __restrict__ btot) {
    __shared__ int sh[256];
    int tid = threadIdx.x, b = blockIdx.x;
    int v = cntmat[b * CSR_BLKS + tid];
    sh[tid] = v;
    __syncthreads();
    for (int o = 1; o < 256; o <<= 1) {
        int t = (tid >= o) ? sh[tid - o] : 0;
        __syncthreads();
        sh[tid] += t;
        __syncthreads();
    }
    exc[b * CSR_BLKS + tid] = sh[tid] - v;
    if (tid == 255) btot[b] = sh[255];
}

// sv = src + et*N (17 bits) | (dst&255)<<17.
__global__ __launch_bounds__(256) void csr2_kernel(const int* __restrict__ src,
                                                   const int* __restrict__ dst,
                                                   const int* __restrict__ et,
                                                   const int* __restrict__ exc,
                                                   const int* __restrict__ btot,
                                                   int* __restrict__ bstart,
                                                   int* __restrict__ esv) {
    __shared__ int sh[256];
    __shared__ int bst[NBUCK];
    __shared__ int cur[NBUCK];
    int tid = threadIdx.x;
    int v = (tid < NBUCK) ? btot[tid] : 0;
    sh[tid] = v;
    __syncthreads();
    for (int o = 1; o < 256; o <<= 1) {
        int t = (tid >= o) ? sh[tid - o] : 0;
        __syncthreads();
        sh[tid] += t;
        __syncthreads();
    }
    if (tid < NBUCK) bst[tid] = sh[tid] - v;
    if (blockIdx.x == 0) {
        if (tid < NBUCK) bstart[tid] = sh[tid] - v;
        if (tid == NBUCK - 1) bstart[NBUCK] = sh[tid];
    }
    __syncthreads();
    if (tid < NBUCK) cur[tid] = exc[tid * CSR_BLKS + blockIdx.x] + bst[tid];
    __syncthreads();
    int base = blockIdx.x * EPB;
#pragma unroll
    for (int i = 0; i < EITER; ++i) {
        int idx = i * 256 + tid;
        if (idx < EPB) {
            int e = base + idx;
            int d = dst[e];
            int pos = atomicAdd(&cur[d >> 8], 1);
            esv[pos] = (src[e] + et[e] * N_NODES) | ((d & 255) << 17);
        }
    }
}

// phase 4: per-bucket finalize. Type-sorted scatter (data first, control
// after). col is uint16 (node id < 65536).
__global__ __launch_bounds__(256) void csr3_kernel(const int* __restrict__ esv,
                                                   const int* __restrict__ bstart,
                                                   unsigned short* __restrict__ col,
                                                   int* __restrict__ row_start,
                                                   int* __restrict__ deg,
                                                   int* __restrict__ degd) {
    __shared__ int cnt[256];
    __shared__ int cntd[256];
    __shared__ int sh[256];
    __shared__ int curD[256];
    __shared__ int curC[256];
    int tid = threadIdx.x, b = blockIdx.x;
    int bs = bstart[b], be = bstart[b + 1];
    cnt[tid] = 0;
    cntd[tid] = 0;
    __syncthreads();
    for (int e = bs + tid; e < be; e += 256) {
        int pk = esv[e];
        int nd = (pk >> 17) & 255;
        atomicAdd(&cnt[nd], 1);
        if ((pk & 0x1FFFF) < N_NODES) atomicAdd(&cntd[nd], 1);
    }
    __syncthreads();
    int v = cnt[tid];
    sh[tid] = v;
    __syncthreads();
    for (int o = 1; o < 256; o <<= 1) {
        int t = (tid >= o) ? sh[tid - o] : 0;
        __syncthreads();
        sh[tid] += t;
        __syncthreads();
    }
    int off  = sh[tid] - v;
    int node = (b << 8) + tid;
    if (node < N_NODES) {
        row_start[node] = bs + off;
        deg[node]       = v;
        degd[node]      = cntd[tid];
    }
    curD[tid] = bs + off;
    curC[tid] = bs + off + cntd[tid];
    __syncthreads();
    for (int e = bs + tid; e < be; e += 256) {
        int pk  = esv[e];
        int nd  = (pk >> 17) & 255;
        int sv  = pk & 0x1FFFF;
        int isC = sv >= N_NODES;
        int pos = atomicAdd(isC ? &curC[nd] : &curD[nd], 1);
        col[pos] = (unsigned short)(sv - (isC ? N_NODES : 0));
    }
}

// ---------------------------------------------------------------- aggregation
// R24: 2-wave (128-thread) blocks for occupancy (R7: 38% occ, VALU 40% --
// under-occupied latency/VALU mix). 32 nodes/block, 4 lanes/node, slice =
// blockIdx%4 (XCD k = b%8 sees slice k%4 only -> L2-resident 1.6MB region).
__device__ __forceinline__ void agg_range(
        const unsigned short* __restrict__ col,
        const unsigned char* __restrict__ Xs,
        unsigned off, int base, int cnt, float* a) {
    if (cnt <= 0) return;
    int last = cnt - 1;
    int nb = (cnt + 7) >> 3;
    int p[8];
#pragma unroll
    for (int i = 0; i < 8; ++i)
        p[i] = col[base + (i < cnt ? i : last)];
    for (int b = 0; b < nb; ++b) {
        int e0 = b * 8;
        uint2 v[8];
#pragma unroll
        for (int i = 0; i < 8; ++i)
            v[i] = *(const uint2*)(Xs + (((unsigned)p[i] * SLB) | off));
        // prefetch next burst's column indices before consuming v[]
        int pn[8];
        if (b + 1 < nb) {
            int e1 = e0 + 8;
#pragma unroll
            for (int i = 0; i < 8; ++i) {
                int idx = e1 + i;
                pn[i] = col[base + (idx < cnt ? idx : last)];
            }
        }
#pragma unroll
        for (int i = 0; i < 8; ++i)
            if (e0 + i >= cnt) { v[i].x = 0u; v[i].y = 0u; }  // e4m3 0x00 == +0.0
#pragma unroll
        for (int i = 0; i < 8; ++i) {
            f32x2 f0 = __builtin_amdgcn_cvt_pk_f32_fp8(v[i].x, false);
            f32x2 f1 = __builtin_amdgcn_cvt_pk_f32_fp8(v[i].x, true);
            f32x2 f2 = __builtin_amdgcn_cvt_pk_f32_fp8(v[i].y, false);
            f32x2 f3 = __builtin_amdgcn_cvt_pk_f32_fp8(v[i].y, true);
            a[0] += f0[0]; a[1] += f0[1];
            a[2] += f1[0]; a[3] += f1[1];
            a[4] += f2[0]; a[5] += f2[1];
            a[6] += f3[0]; a[7] += f3[1];
        }
        if (b + 1 < nb) {
#pragma unroll
            for (int i = 0; i < 8; ++i) p[i] = pn[i];
        }
    }
}

__global__ __launch_bounds__(128) void agg_kernel(
        const int* __restrict__ row_start, const int* __restrict__ deg_arr,
        const int* __restrict__ degd_arr,
        const unsigned short* __restrict__ col,
        const unsigned char* __restrict__ X8t,
        __half* __restrict__ Sd, __half* __restrict__ Sc) {
    int b    = blockIdx.x;
    int s    = b & (NSLICE - 1);       // slice; XCD k = b%8 gets slice k%4
    int nb   = b >> 2;                 // node-block
    int tid  = threadIdx.x;            // 0..127
    int nl   = tid >> 2;               // node within block (32 per block)
    int l4   = tid & 3;                // lane within node
    int node = nb * 32 + nl;
    if (node >= N_NODES) return;

    int rs = row_start[node];
    int dg = deg_arr[node];
    int dd = degd_arr[node];
    const unsigned char* Xs = X8t + (size_t)s * SLICE_BYTES;
    const unsigned off = (unsigned)l4 * 8;   // 8 fp8 cols per lane, within slice

    float aD[8], aC[8];
#pragma unroll
    for (int j = 0; j < 8; ++j) { aD[j] = 0.f; aC[j] = 0.f; }

    agg_range(col, Xs, off, rs, dd, aD);
    agg_range(col, Xs, off, rs + dd, dg - dd, aC);

    union { __half2 h2[4]; uint4 u; } pd, pc;
#pragma unroll
    for (int j = 0; j < 4; ++j) {
        pd.h2[j] = __floats2half2_rn(aD[2 * j], aD[2 * j + 1]);
        pc.h2[j] = __floats2half2_rn(aC[2 * j], aC[2 * j + 1]);
    }
    size_t so = (size_t)node * DIM + s * SLB + l4 * 8;
    *(uint4*)(Sd + so) = pd.u;
    *(uint4*)(Sc + so) = pc.u;
}

// ---------------------------------------------------------------- fused GEMM
// X_next = ReLU(Sd*Wd + Sc*Wc + X*Ws + degd*bd + degc*bc + bs).
// Swapped MFMA operands (R22, verified): acc = C^T, lane = node row.
// R24: register-prefetch pipeline -- tile (w+1)'s A/B global loads issue
// BEFORE tile w's MFMA block (HBM latency hides under MFMA); reg->LDS
// write happens after the post-MFMA barrier. LDS unchanged (52KB, 3/CU).
__global__ __launch_bounds__(256) void gemm_fused_kernel(
        const __half* __restrict__ Sd, const __half* __restrict__ Sc,
        const __half* __restrict__ Xh,
        const __half* __restrict__ WTl,  // [3][128 n][128 k] fp16, this layer
        const float* __restrict__ bd, const float* __restrict__ bc,
        const float* __restrict__ bs,
        const int* __restrict__ degd, const int* __restrict__ deg,
        __half* __restrict__ Xh_out, unsigned char* __restrict__ X8_out,
        int write8) {
    __shared__ _Float16 As[64 * LDK];
    __shared__ _Float16 Bs[128 * LDK];

    const int tid = threadIdx.x;
    const int m0  = blockIdx.x * 64;

    const int wv = tid >> 6;
    const int l  = tid & 63;
    const int lm = l & 15;
    const int q  = l >> 4;

    // staging coords (A: 4 chunks of 64 rows; B: 8 chunks of 128 rows)
    const int arow[4] = { (0 * 256 + tid) >> 4, (1 * 256 + tid) >> 4,
                          (2 * 256 + tid) >> 4, (3 * 256 + tid) >> 4 };
    const int acol = (tid & 15) * 8;

    f32x4 acc[4][2];
#pragma unroll
    for (int mt = 0; mt < 4; ++mt) {
        acc[mt][0] = (f32x4){0.f, 0.f, 0.f, 0.f};
        acc[mt][1] = (f32x4){0.f, 0.f, 0.f, 0.f};
    }

    // ---- stage w=0 (Sd, W0)
    {
        uint4 a0[4], b0[8];
#pragma unroll
        for (int i = 0; i < 4; ++i) {
            int gr = m0 + arow[i];
            a0[i] = make_uint4(0u, 0u, 0u, 0u);
            if (gr < N_NODES) a0[i] = *(const uint4*)(Sd + (size_t)gr * DIM + acol);
        }
#pragma unroll
        for (int i = 0; i < 8; ++i) {
            int c = i * 256 + tid;
            b0[i] = *(const uint4*)(WTl + (size_t)(c >> 4) * DIM + (c & 15) * 8);
        }
#pragma unroll
        for (int i = 0; i < 4; ++i)
            *(uint4*)(As + arow[i] * LDK + acol) = a0[i];
#pragma unroll
        for (int i = 0; i < 8; ++i) {
            int c = i * 256 + tid;
            *(uint4*)(Bs + (c >> 4) * LDK + (c & 15) * 8) = b0[i];
        }
    }
    __syncthreads();

#pragma unroll
    for (int w = 0; w < 3; ++w) {
        // ---- prefetch next tile's A/B to registers (issue before MFMA)
        uint4 a_pf[4], b_pf[8];
        if (w < 2) {
            const __half* An = (w == 0) ? Sc : Xh;
#pragma unroll
            for (int i = 0; i < 4; ++i) {
                int gr = m0 + arow[i];
                a_pf[i] = make_uint4(0u, 0u, 0u, 0u);
                if (gr < N_NODES)
                    a_pf[i] = *(const uint4*)(An + (size_t)gr * DIM + acol);
            }
            const __half* Wn = WTl + (size_t)(w + 1) * DIM * DIM;
#pragma unroll
            for (int i = 0; i < 8; ++i) {
                int c = i * 256 + tid;
                b_pf[i] = *(const uint4*)(Wn + (size_t)(c >> 4) * DIM + (c & 15) * 8);
            }
        }

        // ---- MFMA over current LDS tiles
#pragma unroll
        for (int ks = 0; ks < 4; ++ks) {
            int coff = ks * 32 + q * 8;
            half8 am[4];
#pragma unroll
            for (int mt = 0; mt < 4; ++mt)
                am[mt] = *(const half8*)(As + (mt * 16 + lm) * LDK + coff);
            half8 bb0 = *(const half8*)(Bs + (wv * 32 + lm) * LDK + coff);
            half8 bb1 = *(const half8*)(Bs + (wv * 32 + 16 + lm) * LDK + coff);
            // swapped operands: acc = C^T (lane = node, reg = feature)
#pragma unroll
            for (int mt = 0; mt < 4; ++mt) {
                acc[mt][0] = __builtin_amdgcn_mfma_f32_16x16x32_f16(bb0, am[mt], acc[mt][0], 0, 0, 0);
                acc[mt][1] = __builtin_amdgcn_mfma_f32_16x16x32_f16(bb1, am[mt], acc[mt][1], 0, 0, 0);
            }
        }

        // ---- rotate: write prefetched regs into LDS
        if (w < 2) {
            __syncthreads();   // all MFMA reads of As/Bs done
#pragma unroll
            for (int i = 0; i < 4; ++i)
                *(uint4*)(As + arow[i] * LDK + acol) = a_pf[i];
#pragma unroll
            for (int i = 0; i < 8; ++i) {
                int c = i * 256 + tid;
                *(uint4*)(Bs + (c >> 4) * LDK + (c & 15) * 8) = b_pf[i];
            }
            __syncthreads();   // new tiles visible
        }
    }

    // ------------- epilogue: deg-weighted biases + ReLU + packed stores
    const int fb0 = wv * 32 + q * 4;   // features for nt=0 (4 consecutive)
    const int fb1 = fb0 + 16;          // features for nt=1
    f32x4 bdv0 = *(const f32x4*)(bd + fb0), bdv1 = *(const f32x4*)(bd + fb1);
    f32x4 bcv0 = *(const f32x4*)(bc + fb0), bcv1 = *(const f32x4*)(bc + fb1);
    f32x4 bsv0 = *(const f32x4*)(bs + fb0), bsv1 = *(const f32x4*)(bs + fb1);
#pragma unroll
    for (int mt = 0; mt < 4; ++mt) {
        int row = m0 + mt * 16 + lm;
        if (row < N_NODES) {
            float dd = (float)degd[row];
            float dc = (float)(deg[row] - degd[row]);
            float v0[4], v1[4];
#pragma unroll
            for (int r = 0; r < 4; ++r) {
                v0[r] = fmaxf(acc[mt][0][r] + dd * bdv0[r] + dc * bcv0[r] + bsv0[r], 0.f);
                v1[r] = fmaxf(acc[mt][1][r] + dd * bdv1[r] + dc * bcv1[r] + bsv1[r], 0.f);
            }
            union { __half2 h2[2]; uint2 u; } p0, p1;
            p0.h2[0] = __floats2half2_rn(v0[0], v0[1]);
            p0.h2[1] = __floats2half2_rn(v0[2], v0[3]);
            p1.h2[0] = __floats2half2_rn(v1[0], v1[1]);
            p1.h2[1] = __floats2half2_rn(v1[2], v1[3]);
            *(uint2*)(Xh_out + (size_t)row * DIM + fb0) = p0.u;
            *(uint2*)(Xh_out + (size_t)row * DIM + fb1) = p1.u;
            if (write8) {
                int q0 = __builtin_amdgcn_cvt_pk_fp8_f32(v0[0], v0[1], 0, false);
                q0 = __builtin_amdgcn_cvt_pk_fp8_f32(v0[2], v0[3], q0, true);
                int q1 = __builtin_amdgcn_cvt_pk_fp8_f32(v1[0], v1[1], 0, false);
                q1 = __builtin_amdgcn_cvt_pk_fp8_f32(v1[2], v1[3], q1, true);
                // slice-major: slice = wv, bytes q*4 and q*4+16 within it
                unsigned char* xb = X8_out + (size_t)wv * SLICE_BYTES
                                  + (size_t)row * SLB;
                *(unsigned int*)(xb + q * 4)      = (unsigned)q0;
                *(unsigned int*)(xb + q * 4 + 16) = (unsigned)q1;
            }
        }
    }
}

// ---------------------------------------------------------------- pooling
__global__ __launch_bounds__(256) void pool_kernel(const __half* __restrict__ X,
                                                   const int* __restrict__ bid,
                                                   float* __restrict__ sums,
                                                   int* __restrict__ gcnt) {
    __shared__ float acc[8][DIM];
    __shared__ int scnt[8];
    __shared__ int sgmin;
    int tid = threadIdx.x;
    for (int i = tid; i < 8 * DIM; i += 256) ((float*)acc)[i] = 0.f;
    if (tid < 8) scnt[tid] = 0;
    int n0 = blockIdx.x * 64;
    if (tid == 0) sgmin = bid[n0];
    __syncthreads();
    int gmin = sgmin;

    int s    = tid >> 5;
    int lane = tid & 31;
    int r0   = n0 + s * 8;

    int g[8];
    union { uint2 u; __half2 h2[2]; } v[8];
#pragma unroll
    for (int i = 0; i < 8; ++i) {
        int r = r0 + i;
        g[i] = (r < N_NODES) ? bid[r] : -1;
    }
#pragma unroll
    for (int i = 0; i < 8; ++i) {
        int r = r0 + i;
        if (r < N_NODES)
            v[i].u = *(const uint2*)(X + (size_t)r * DIM + lane * 4);
        else { v[i].u.x = 0u; v[i].u.y = 0u; }
    }

    float4 a = make_float4(0.f, 0.f, 0.f, 0.f);
    int cur = -1, run = 0;
#pragma unroll
    for (int i = 0; i < 8; ++i) {
        if (g[i] != cur) {
            if (cur >= 0) {
                int slot = cur - gmin;
                if (slot < 8) {
                    atomicAdd(&acc[slot][lane * 4 + 0], a.x);
                    atomicAdd(&acc[slot][lane * 4 + 1], a.y);
                    atomicAdd(&acc[slot][lane * 4 + 2], a.z);
                    atomicAdd(&acc[slot][lane * 4 + 3], a.w);
                    if (lane == 0) atomicAdd(&scnt[slot], run);
                } else {
                    atomicAdd(&sums[cur * DIM + lane * 4 + 0], a.x);
                    atomicAdd(&sums[cur * DIM + lane * 4 + 1], a.y);
                    atomicAdd(&sums[cur * DIM + lane * 4 + 2], a.z);
                    atomicAdd(&sums[cur * DIM + lane * 4 + 3], a.w);
                    if (lane == 0) atomicAdd(&gcnt[cur], run);
                }
            }
            cur = g[i];
            a = make_float4(0.f, 0.f, 0.f, 0.f);
            run = 0;
        }
        if (g[i] >= 0) {
            float2 f0 = __half22float2(v[i].h2[0]);
            float2 f1 = __half22float2(v[i].h2[1]);
            a.x += f0.x; a.y += f0.y; a.z += f1.x; a.w += f1.y;
            run++;
        }
    }
    if (cur >= 0) {
        int slot = cur - gmin;
        if (slot < 8) {
            atomicAdd(&acc[slot][lane * 4 + 0], a.x);
            atomicAdd(&acc[slot][lane * 4 + 1], a.y);
            atomicAdd(&acc[slot][lane * 4 + 2], a.z);
            atomicAdd(&acc[slot][lane * 4 + 3], a.w);
            if (lane == 0) atomicAdd(&scnt[slot], run);
        } else {
            atomicAdd(&sums[cur * DIM + lane * 4 + 0], a.x);
            atomicAdd(&sums[cur * DIM + lane * 4 + 1], a.y);
            atomicAdd(&sums[cur * DIM + lane * 4 + 2], a.z);
            atomicAdd(&sums[cur * DIM + lane * 4 + 3], a.w);
            if (lane == 0) atomicAdd(&gcnt[cur], run);
        }
    }
    __syncthreads();

    for (int slot = 0; slot < 8; ++slot) {
        if (scnt[slot] > 0) {
            int gg = gmin + slot;
            for (int i = tid; i < DIM; i += 256)
                atomicAdd(&sums[gg * DIM + i], acc[slot][i]);
            if (tid == 0) atomicAdd(&gcnt[gg], scnt[slot]);
        }
    }
}

__global__ __launch_bounds__(256) void div_kernel(const float* __restrict__ sums,
                                                  const int* __restrict__ gcnt,
                                                  float* __restrict__ out) {
    int i = blockIdx.x * 256 + threadIdx.x;
    if (i < NGRAPHS * DIM) {
        int g = i >> 7;
        out[i] = sums[i] / fmaxf((float)gcnt[g], 1.f);
    }
}

// ---------------------------------------------------------------- launcher
extern "C" void kernel_launch(void* const* d_in, const int* in_sizes, int n_in,
                              void* d_out, int out_size, void* d_ws, size_t ws_size,
                              hipStream_t stream) {
    const float* Xin = (const float*)d_in[0];
    const float* Wd  = (const float*)d_in[1];
    const float* bd  = (const float*)d_in[2];
    const float* Wc  = (const float*)d_in[3];
    const float* bc  = (const float*)d_in[4];
    const float* Ws  = (const float*)d_in[5];
    const float* bs  = (const float*)d_in[6];
    const int* edge_index = (const int*)d_in[7];
    const int* edge_types = (const int*)d_in[8];
    const int* batch_ids  = (const int*)d_in[9];

    const int* src = edge_index;
    const int* dst = edge_index + N_EDGES;

    const size_t NBH = (size_t)N_NODES * DIM * sizeof(__half);  // 12.8 MB
    const size_t NB8 = (size_t)N_NODES * DIM;                   // 6.4 MB fp8
    char* w = (char*)d_ws;
    auto take = [&](size_t bytes) {
        char* p = w;
        w += (bytes + 255) & ~(size_t)255;
        return p;
    };
    __half* Xh0  = (__half*)take(NBH);
    __half* Xh1  = (__half*)take(NBH);
    unsigned char* X8a = (unsigned char*)take(NB8);
    unsigned char* X8b = (unsigned char*)take(NB8);
    __half* SdB  = (__half*)take(NBH);
    __half* ScB  = (__half*)take(NBH);
    __half* WT   = (__half*)take((size_t)9 * DIM * DIM * sizeof(__half));
    unsigned short* col = (unsigned short*)take((size_t)N_EDGES * 2);
    int* esv     = (int*)take((size_t)N_EDGES * 4);
    int* cntmat  = (int*)take((size_t)NBUCK * CSR_BLKS * 4);
    int* exc     = (int*)take((size_t)NBUCK * CSR_BLKS * 4);
    int* btot    = (int*)take((size_t)NBUCK * 4);
    int* bstart  = (int*)take((size_t)(NBUCK + 1) * 4);
    int* rowst   = (int*)take((size_t)N_NODES * 4);
    int* deg     = (int*)take((size_t)N_NODES * 4);
    int* degd    = (int*)take((size_t)N_NODES * 4);
    float* sums  = (float*)take((size_t)NGRAPHS * DIM * 4);
    int* gcnt    = (int*)take(NGRAPHS * 4);

    setup_kernel<<<(N_NODES * DIM / 4 + 255) / 256, 256, 0, stream>>>(
        Xin, Xh0, X8a, Wd, Wc, Ws, WT, sums, gcnt);

    csr1_kernel<<<CSR_BLKS, 256, 0, stream>>>(dst, cntmat);
    scanA_kernel<<<NBUCK, 256, 0, stream>>>(cntmat, exc, btot);
    csr2_kernel<<<CSR_BLKS, 256, 0, stream>>>(src, dst, edge_types, exc,
                                              btot, bstart, esv);
    csr3_kernel<<<NBUCK, 256, 0, stream>>>(esv, bstart, col, rowst, deg, degd);

    const int GEMM_MBLK = (N_NODES + 63) / 64;               // 782
    const int AGG_BLKS  = ((N_NODES + 31) / 32) * NSLICE;    // 6252

    const __half*      Xhc = Xh0;
    const unsigned char* X8c = X8a;
    __half*            XhN[3] = {Xh1, Xh0, Xh1};
    unsigned char*     X8N[3] = {X8b, X8a, X8b};
    for (int l = 0; l < NLAYERS; ++l) {
        agg_kernel<<<AGG_BLKS, 128, 0, stream>>>(rowst, deg, degd, col, X8c,
                                                 SdB, ScB);
        gemm_fused_kernel<<<GEMM_MBLK, 256, 0, stream>>>(
            SdB, ScB, Xhc, WT + (size_t)l * 3 * DIM * DIM,
            bd + (size_t)l * DIM, bc + (size_t)l * DIM, bs + (size_t)l * DIM,
            degd, deg, XhN[l], X8N[l], (l < NLAYERS - 1) ? 1 : 0);
        Xhc = XhN[l];
        X8c = X8N[l];
    }

    const int POOL_BLKS = (N_NODES + 63) / 64;  // 782
    pool_kernel<<<POOL_BLKS, 256, 0, stream>>>(Xhc, batch_ids, sums, gcnt);
    div_kernel<<<(NGRAPHS * DIM + 255) / 256, 256, 0, stream>>>(sums, gcnt,
                                                                (float*)d_out);
}

// Round 9
// 312.774 us; speedup vs baseline: 1.2311x; 1.2311x over previous
//
#include <hip/hip_runtime.h>
#include <hip/hip_fp16.h>

#define N_NODES 50000
#define N_EDGES 1600000
#define DIM     128
#define NLAYERS 3
#define NGRAPHS 64

#define NBUCK   196            // buckets of 256 nodes: bucket = dst >> 8
#define CSR_BLKS 256
#define EPB     (N_EDGES / CSR_BLKS)   // 6250 edges per csr block
#define EITER   ((EPB + 255) / 256)    // 25

typedef _Float16 half8 __attribute__((ext_vector_type(8)));
typedef float    f32x4 __attribute__((ext_vector_type(4)));
typedef float    f32x2 __attribute__((ext_vector_type(2)));

#define LDK 136   // padded halves/row: 272B stride (16B-aligned), rotates banks

// ---------------------------------------------------------------- setup
__global__ __launch_bounds__(256) void setup_kernel(
        const float* __restrict__ X, __half* __restrict__ Xh,
        const float* __restrict__ Wd, const float* __restrict__ Wc,
        const float* __restrict__ Ws, __half* __restrict__ WT,
        float* __restrict__ sums, int* __restrict__ gcnt) {
    int i = blockIdx.x * 256 + threadIdx.x;
    if (i < N_NODES * DIM / 4) {
        float4 v = *(const float4*)(X + (size_t)i * 4);
        union { __half2 h2[2]; uint2 u; } pk;
        pk.h2[0] = __floats2half2_rn(v.x, v.y);
        pk.h2[1] = __floats2half2_rn(v.z, v.w);
        *(uint2*)(Xh + (size_t)i * 4) = pk.u;
    }
    if (i < 9 * DIM * DIM) {   // WT[(l*3+w)][n][k] = W[l][k][n]
        int k  = i & 127;
        int n  = (i >> 7) & 127;
        int lw = i >> 14;
        int l  = lw / 3, w = lw - 3 * l;
        const float* W = ((w == 0) ? Wd : (w == 1) ? Wc : Ws)
                         + (size_t)l * DIM * DIM;
        WT[i] = __float2half(W[k * DIM + n]);
    }
    if (i < NGRAPHS * DIM) sums[i] = 0.f;
    if (i < NGRAPHS) gcnt[i] = 0;
}

// ---------------------------------------------------------------- CSR build
// Two-level counting sort, zero global atomics (R7 lesson: 1.6M device
// atomics cost 56 MB HBM RMW regardless of locality).
__global__ __launch_bounds__(256) void csr1_kernel(const int* __restrict__ dst,
                                                   int* __restrict__ cntmat) {
    __shared__ int hc[NBUCK];
    int tid = threadIdx.x;
    for (int i = tid; i < NBUCK; i += 256) hc[i] = 0;
    __syncthreads();
    int base = blockIdx.x * EPB;
#pragma unroll
    for (int i = 0; i < EITER; ++i) {
        int idx = i * 256 + tid;
        if (idx < EPB) atomicAdd(&hc[dst[base + idx] >> 8], 1);
    }
    __syncthreads();
    for (int i = tid; i < NBUCK; i += 256)
        cntmat[i * CSR_BLKS + blockIdx.x] = hc[i];
}

__global__ __launch_bounds__(256) void scanA_kernel(const int* __restrict__ cntmat,
                                                    int* __restrict__ exc,
                                                    int* __restrict__ btot) {
    __shared__ int sh[256];
    int tid = threadIdx.x, b = blockIdx.x;
    int v = cntmat[b * CSR_BLKS + tid];
    sh[tid] = v;
    __syncthreads();
    for (int o = 1; o < 256; o <<= 1) {
        int t = (tid >= o) ? sh[tid - o] : 0;
        __syncthreads();
        sh[tid] += t;
        __syncthreads();
    }
    exc[b * CSR_BLKS + tid] = sh[tid] - v;
    if (tid == 255) btot[b] = sh[255];
}

// scanB folded in; edge record packed into ONE int (R16):
// sv = src + et*N (17 bits) | (dst&255)<<17.
__global__ __launch_bounds__(256) void csr2_kernel(const int* __restrict__ src,
                                                   const int* __restrict__ dst,
                                                   const int* __restrict__ et,
                                                   const int* __restrict__ exc,
                                                   const int* __restrict__ btot,
                                                   int* __restrict__ bstart,
                                                   int* __restrict__ esv) {
    __shared__ int sh[256];
    __shared__ int bst[NBUCK];
    __shared__ int cur[NBUCK];
    int tid = threadIdx.x;
    int v = (tid < NBUCK) ? btot[tid] : 0;
    sh[tid] = v;
    __syncthreads();
    for (int o = 1; o < 256; o <<= 1) {
        int t = (tid >= o) ? sh[tid - o] : 0;
        __syncthreads();
        sh[tid] += t;
        __syncthreads();
    }
    if (tid < NBUCK) bst[tid] = sh[tid] - v;
    if (blockIdx.x == 0) {
        if (tid < NBUCK) bstart[tid] = sh[tid] - v;
        if (tid == NBUCK - 1) bstart[NBUCK] = sh[tid];
    }
    __syncthreads();
    if (tid < NBUCK) cur[tid] = exc[tid * CSR_BLKS + blockIdx.x] + bst[tid];
    __syncthreads();
    int base = blockIdx.x * EPB;
#pragma unroll
    for (int i = 0; i < EITER; ++i) {
        int idx = i * 256 + tid;
        if (idx < EPB) {
            int e = base + idx;
            int d = dst[e];
            int pos = atomicAdd(&cur[d >> 8], 1);
            esv[pos] = (src[e] + et[e] * N_NODES) | ((d & 255) << 17);
        }
    }
}

// phase 4: per-bucket finalize (LDS count -> scan -> row_start/deg -> scatter)
__global__ __launch_bounds__(256) void csr3_kernel(const int* __restrict__ esv,
                                                   const int* __restrict__ bstart,
                                                   int* __restrict__ col,
                                                   int* __restrict__ row_start,
                                                   int* __restrict__ deg) {
    __shared__ int cnt[256];
    __shared__ int sh[256];
    __shared__ int cur[256];
    int tid = threadIdx.x, b = blockIdx.x;
    int bs = bstart[b], be = bstart[b + 1];
    cnt[tid] = 0;
    __syncthreads();
    for (int e = bs + tid; e < be; e += 256)
        atomicAdd(&cnt[(esv[e] >> 17) & 255], 1);
    __syncthreads();
    int v = cnt[tid];
    sh[tid] = v;
    __syncthreads();
    for (int o = 1; o < 256; o <<= 1) {
        int t = (tid >= o) ? sh[tid - o] : 0;
        __syncthreads();
        sh[tid] += t;
        __syncthreads();
    }
    int off  = sh[tid] - v;
    int node = (b << 8) + tid;
    if (node < N_NODES) {
        row_start[node] = bs + off;
        deg[node]       = v;
    }
    cur[tid] = bs + off;
    __syncthreads();
    for (int e = bs + tid; e < be; e += 256) {
        int pk  = esv[e];
        int nd  = (pk >> 17) & 255;
        int pos = atomicAdd(&cur[nd], 1);
        col[pos] = pk & 0x1FFFF;
    }
}

// ---------------------------------------------------------------- MFMA GEMM
// R2-measured structure (64-row tile, blockIdx.y = w, fp8 Od/Oc + fp16 Sh).
// R25 change (the ONLY change vs the 307us R2 baseline): swapped-operand
// MFMA -- mfma(bb, am, acc) computes C^T, so lane = node row and the 4 acc
// regs = 4 CONSECUTIVE features. Bias becomes a f32x4 init; epilogue is 8
// packed stores/thread (4B fp8 or 8B fp16) instead of 32 scalar stores.
// Swap verified correct on-harness in R6 (passed, absmax 4.0).
__global__ __launch_bounds__(256) void gemm3m_kernel(
        const __half* __restrict__ Xh,   // [N][128] fp16
        const __half* __restrict__ WTl,  // [3][128 n][128 k] fp16, this layer
        const float* __restrict__ bd, const float* __restrict__ bc,
        const float* __restrict__ bs,
        unsigned char* __restrict__ Od, unsigned char* __restrict__ Oc,
        __half* __restrict__ Sh) {
    __shared__ _Float16 As[64 * LDK];
    __shared__ _Float16 Bs[128 * LDK];

    const int tid = threadIdx.x;
    const int m0  = blockIdx.x * 64;
    const int w   = blockIdx.y;

#pragma unroll
    for (int i = 0; i < 4; ++i) {
        int c    = i * 256 + tid;
        int row  = c >> 4;
        int colh = (c & 15) * 8;
        uint4 v  = make_uint4(0u, 0u, 0u, 0u);
        int gr   = m0 + row;
        if (gr < N_NODES) v = *(const uint4*)(Xh + (size_t)gr * DIM + colh);
        *(uint4*)(As + row * LDK + colh) = v;
    }
    {
        const __half* Wt = WTl + (size_t)w * DIM * DIM;
#pragma unroll
        for (int i = 0; i < 8; ++i) {
            int c    = i * 256 + tid;
            int row  = c >> 4;
            int colh = (c & 15) * 8;
            uint4 v = *(const uint4*)(Wt + (size_t)row * DIM + colh);
            *(uint4*)(Bs + row * LDK + colh) = v;
        }
    }
    __syncthreads();

    const int wv = tid >> 6;
    const int l  = tid & 63;
    const int lm = l & 15;
    const int q  = l >> 4;

    // feature blocks (4 consecutive features per acc register group)
    const int fb0 = wv * 32 + q * 4;   // nt=0
    const int fb1 = fb0 + 16;          // nt=1

    const float* bias = (w == 0) ? bd : (w == 1) ? bc : bs;
    f32x4 acc[4][2];
    {
        f32x4 bi0 = *(const f32x4*)(bias + fb0);
        f32x4 bi1 = *(const f32x4*)(bias + fb1);
#pragma unroll
        for (int mt = 0; mt < 4; ++mt) {
            acc[mt][0] = bi0;
            acc[mt][1] = bi1;
        }
    }

#pragma unroll
    for (int ks = 0; ks < 4; ++ks) {
        int coff = ks * 32 + q * 8;
        half8 am[4];
#pragma unroll
        for (int mt = 0; mt < 4; ++mt)
            am[mt] = *(const half8*)(As + (mt * 16 + lm) * LDK + coff);
        half8 bb0 = *(const half8*)(Bs + (wv * 32 + lm) * LDK + coff);
        half8 bb1 = *(const half8*)(Bs + (wv * 32 + 16 + lm) * LDK + coff);
        // swapped operands: acc = C^T (lane = node, regs = 4 features)
#pragma unroll
        for (int mt = 0; mt < 4; ++mt) {
            acc[mt][0] = __builtin_amdgcn_mfma_f32_16x16x32_f16(bb0, am[mt], acc[mt][0], 0, 0, 0);
            acc[mt][1] = __builtin_amdgcn_mfma_f32_16x16x32_f16(bb1, am[mt], acc[mt][1], 0, 0, 0);
        }
    }

    if (w < 2) {
        unsigned char* O = (w == 0) ? Od : Oc;
#pragma unroll
        for (int mt = 0; mt < 4; ++mt) {
            int row = m0 + mt * 16 + lm;
            if (row < N_NODES) {
                int q0 = __builtin_amdgcn_cvt_pk_fp8_f32(acc[mt][0][0], acc[mt][0][1], 0, false);
                q0 = __builtin_amdgcn_cvt_pk_fp8_f32(acc[mt][0][2], acc[mt][0][3], q0, true);
                int q1 = __builtin_amdgcn_cvt_pk_fp8_f32(acc[mt][1][0], acc[mt][1][1], 0, false);
                q1 = __builtin_amdgcn_cvt_pk_fp8_f32(acc[mt][1][2], acc[mt][1][3], q1, true);
                *(unsigned int*)(O + (size_t)row * DIM + fb0) = (unsigned)q0;
                *(unsigned int*)(O + (size_t)row * DIM + fb1) = (unsigned)q1;
            }
        }
    } else {
#pragma unroll
        for (int mt = 0; mt < 4; ++mt) {
            int row = m0 + mt * 16 + lm;
            if (row < N_NODES) {
                union { __half2 h2[2]; uint2 u; } p0, p1;
                p0.h2[0] = __floats2half2_rn(acc[mt][0][0], acc[mt][0][1]);
                p0.h2[1] = __floats2half2_rn(acc[mt][0][2], acc[mt][0][3]);
                p1.h2[0] = __floats2half2_rn(acc[mt][1][0], acc[mt][1][1]);
                p1.h2[1] = __floats2half2_rn(acc[mt][1][2], acc[mt][1][3]);
                *(uint2*)(Sh + (size_t)row * DIM + fb0) = p0.u;
                *(uint2*)(Sh + (size_t)row * DIM + fb1) = p1.u;
            }
        }
    }
}

// ---------------------------------------------------------------- aggregation
// R19 structure exactly as measured at 307us (R2): 4 nodes/wave, 16
// lanes/node, uint2 = 8 fp8 cols/lane, 8-deep clamped+masked bursts,
// next-burst index prefetch, Sh self-term read early. FROZEN: R2-R8
// showed agg ~41us invariant to traffic (89.5 or 14 MB), block size,
// and accumulator count -- gather-issue/latency floor.
__global__ __launch_bounds__(256) void agg_kernel(
        const int* __restrict__ row_start, const int* __restrict__ deg_arr,
        const int* __restrict__ col,
        const unsigned char* __restrict__ Xdc,
        const __half* __restrict__ Sh, __half* __restrict__ Xout) {
    int wave = (blockIdx.x * 256 + threadIdx.x) >> 6;
    int lane = threadIdx.x & 63;
    int grp  = lane >> 4;          // 4 nodes per wave
    int l16  = lane & 15;
    int node = wave * 4 + grp;
    if (node >= N_NODES) return;

    int rs  = row_start[node];
    int deg = deg_arr[node];
    const size_t off = (size_t)l16 * 8;   // 8 cols/lane (fp8 bytes == halves)

    // self-term read issued early; independent of the gather stream
    union { uint4 u; __half2 h2[4]; } sv;
    sv.u = *(const uint4*)(Sh + (size_t)node * DIM + off);

    float acc[8];
#pragma unroll
    for (int j = 0; j < 8; ++j) acc[j] = 0.f;

    if (deg > 0) {
        int dgm1 = deg - 1;
        int nb   = (deg + 7) >> 3;
        int p[8];
#pragma unroll
        for (int i = 0; i < 8; ++i)
            p[i] = col[rs + (i < deg ? i : dgm1)];
        for (int b = 0; b < nb; ++b) {
            int e0 = b * 8;
            uint2 v[8];
#pragma unroll
            for (int i = 0; i < 8; ++i)
                v[i] = *(const uint2*)(Xdc + (size_t)p[i] * DIM + off);
            // prefetch next burst's column indices before consuming v[]
            int pn[8];
            if (b + 1 < nb) {
                int e1 = e0 + 8;
#pragma unroll
                for (int i = 0; i < 8; ++i) {
                    int idx = e1 + i;
                    pn[i] = col[rs + (idx < deg ? idx : dgm1)];
                }
            }
#pragma unroll
            for (int i = 0; i < 8; ++i) {
                if (e0 + i >= deg) { v[i].x = 0u; v[i].y = 0u; }  // e4m3 0x00 == +0.0
            }
#pragma unroll
            for (int i = 0; i < 8; ++i) {
                f32x2 f0 = __builtin_amdgcn_cvt_pk_f32_fp8(v[i].x, false);
                f32x2 f1 = __builtin_amdgcn_cvt_pk_f32_fp8(v[i].x, true);
                f32x2 f2 = __builtin_amdgcn_cvt_pk_f32_fp8(v[i].y, false);
                f32x2 f3 = __builtin_amdgcn_cvt_pk_f32_fp8(v[i].y, true);
                acc[0] += f0[0]; acc[1] += f0[1];
                acc[2] += f1[0]; acc[3] += f1[1];
                acc[4] += f2[0]; acc[5] += f2[1];
                acc[6] += f3[0]; acc[7] += f3[1];
            }
            if (b + 1 < nb) {
#pragma unroll
                for (int i = 0; i < 8; ++i) p[i] = pn[i];
            }
        }
    }

    float s[8];
#pragma unroll
    for (int j = 0; j < 4; ++j) {
        float2 f = __half22float2(sv.h2[j]);
        s[2 * j]     = f.x;
        s[2 * j + 1] = f.y;
    }

    union { __half2 h2[4]; uint4 u; } pk;
#pragma unroll
    for (int j = 0; j < 4; ++j) {
        float r0 = fmaxf(acc[2 * j]     + s[2 * j],     0.f);
        float r1 = fmaxf(acc[2 * j + 1] + s[2 * j + 1], 0.f);
        pk.h2[j] = __floats2half2_rn(r0, r1);
    }
    *(uint4*)(Xout + (size_t)node * DIM + off) = pk.u;
}

// ---------------------------------------------------------------- pooling
// R13-proven; NO device-scope fence. div is its own launch.
__global__ __launch_bounds__(256) void pool_kernel(const __half* __restrict__ X,
                                                   const int* __restrict__ bid,
                                                   float* __restrict__ sums,
                                                   int* __restrict__ gcnt) {
    __shared__ float acc[8][DIM];
    __shared__ int scnt[8];
    __shared__ int sgmin;
    int tid = threadIdx.x;
    for (int i = tid; i < 8 * DIM; i += 256) ((float*)acc)[i] = 0.f;
    if (tid < 8) scnt[tid] = 0;
    int n0 = blockIdx.x * 64;
    if (tid == 0) sgmin = bid[n0];
    __syncthreads();
    int gmin = sgmin;

    int s    = tid >> 5;
    int lane = tid & 31;
    int r0   = n0 + s * 8;

    int g[8];
    union { uint2 u; __half2 h2[2]; } v[8];
#pragma unroll
    for (int i = 0; i < 8; ++i) {
        int r = r0 + i;
        g[i] = (r < N_NODES) ? bid[r] : -1;
    }
#pragma unroll
    for (int i = 0; i < 8; ++i) {
        int r = r0 + i;
        if (r < N_NODES)
            v[i].u = *(const uint2*)(X + (size_t)r * DIM + lane * 4);
        else { v[i].u.x = 0u; v[i].u.y = 0u; }
    }

    float4 a = make_float4(0.f, 0.f, 0.f, 0.f);
    int cur = -1, run = 0;
#pragma unroll
    for (int i = 0; i < 8; ++i) {
        if (g[i] != cur) {
            if (cur >= 0) {
                int slot = cur - gmin;
                if (slot < 8) {
                    atomicAdd(&acc[slot][lane * 4 + 0], a.x);
                    atomicAdd(&acc[slot][lane * 4 + 1], a.y);
                    atomicAdd(&acc[slot][lane * 4 + 2], a.z);
                    atomicAdd(&acc[slot][lane * 4 + 3], a.w);
                    if (lane == 0) atomicAdd(&scnt[slot], run);
                } else {
                    atomicAdd(&sums[cur * DIM + lane * 4 + 0], a.x);
                    atomicAdd(&sums[cur * DIM + lane * 4 + 1], a.y);
                    atomicAdd(&sums[cur * DIM + lane * 4 + 2], a.z);
                    atomicAdd(&sums[cur * DIM + lane * 4 + 3], a.w);
                    if (lane == 0) atomicAdd(&gcnt[cur], run);
                }
            }
            cur = g[i];
            a = make_float4(0.f, 0.f, 0.f, 0.f);
            run = 0;
        }
        if (g[i] >= 0) {
            float2 f0 = __half22float2(v[i].h2[0]);
            float2 f1 = __half22float2(v[i].h2[1]);
            a.x += f0.x; a.y += f0.y; a.z += f1.x; a.w += f1.y;
            run++;
        }
    }
    if (cur >= 0) {
        int slot = cur - gmin;
        if (slot < 8) {
            atomicAdd(&acc[slot][lane * 4 + 0], a.x);
            atomicAdd(&acc[slot][lane * 4 + 1], a.y);
            atomicAdd(&acc[slot][lane * 4 + 2], a.z);
            atomicAdd(&acc[slot][lane * 4 + 3], a.w);
            if (lane == 0) atomicAdd(&scnt[slot], run);
        } else {
            atomicAdd(&sums[cur * DIM + lane * 4 + 0], a.x);
            atomicAdd(&sums[cur * DIM + lane * 4 + 1], a.y);
            atomicAdd(&sums[cur * DIM + lane * 4 + 2], a.z);
            atomicAdd(&sums[cur * DIM + lane * 4 + 3], a.w);
            if (lane == 0) atomicAdd(&gcnt[cur], run);
        }
    }
    __syncthreads();

    for (int slot = 0; slot < 8; ++slot) {
        if (scnt[slot] > 0) {
            int gg = gmin + slot;
            for (int i = tid; i < DIM; i += 256)
                atomicAdd(&sums[gg * DIM + i], acc[slot][i]);
            if (tid == 0) atomicAdd(&gcnt[gg], scnt[slot]);
        }
    }
}

__global__ __launch_bounds__(256) void div_kernel(const float* __restrict__ sums,
                                                  const int* __restrict__ gcnt,
                                                  float* __restrict__ out) {
    int i = blockIdx.x * 256 + threadIdx.x;
    if (i < NGRAPHS * DIM) {
        int g = i >> 7;
        out[i] = sums[i] / fmaxf((float)gcnt[g], 1.f);
    }
}

// ---------------------------------------------------------------- launcher
extern "C" void kernel_launch(void* const* d_in, const int* in_sizes, int n_in,
                              void* d_out, int out_size, void* d_ws, size_t ws_size,
                              hipStream_t stream) {
    const float* Xin = (const float*)d_in[0];
    const float* Wd  = (const float*)d_in[1];
    const float* bd  = (const float*)d_in[2];
    const float* Wc  = (const float*)d_in[3];
    const float* bc  = (const float*)d_in[4];
    const float* Ws  = (const float*)d_in[5];
    const float* bs  = (const float*)d_in[6];
    const int* edge_index = (const int*)d_in[7];
    const int* edge_types = (const int*)d_in[8];
    const int* batch_ids  = (const int*)d_in[9];

    const int* src = edge_index;
    const int* dst = edge_index + N_EDGES;

    const size_t NBH = (size_t)N_NODES * DIM * sizeof(__half);  // 12.8 MB
    const size_t NB8 = (size_t)N_NODES * DIM;                   // 6.4 MB fp8
    char* w = (char*)d_ws;
    auto take = [&](size_t bytes) {
        char* p = w;
        w += (bytes + 255) & ~(size_t)255;
        return p;
    };
    __half* X0h  = (__half*)take(NBH);
    __half* Xb0h = (__half*)take(NBH);
    __half* Xb1h = (__half*)take(NBH);
    unsigned char* Xdc = (unsigned char*)take(2 * NB8);  // fp8: Xd rows 0..N, Xc N..2N
    __half* Shb  = (__half*)take(NBH);
    __half* WT   = (__half*)take((size_t)9 * DIM * DIM * sizeof(__half));
    int* col     = (int*)take((size_t)N_EDGES * 4);
    int* esv     = (int*)take((size_t)N_EDGES * 4);
    int* cntmat  = (int*)take((size_t)NBUCK * CSR_BLKS * 4);
    int* exc     = (int*)take((size_t)NBUCK * CSR_BLKS * 4);
    int* btot    = (int*)take((size_t)NBUCK * 4);
    int* bstart  = (int*)take((size_t)(NBUCK + 1) * 4);
    int* rowst   = (int*)take((size_t)N_NODES * 4);
    int* deg     = (int*)take((size_t)N_NODES * 4);
    float* sums  = (float*)take((size_t)NGRAPHS * DIM * 4);
    int* gcnt    = (int*)take(NGRAPHS * 4);

    setup_kernel<<<(N_NODES * DIM / 4 + 255) / 256, 256, 0, stream>>>(
        Xin, X0h, Wd, Wc, Ws, WT, sums, gcnt);

    csr1_kernel<<<CSR_BLKS, 256, 0, stream>>>(dst, cntmat);
    scanA_kernel<<<NBUCK, 256, 0, stream>>>(cntmat, exc, btot);
    csr2_kernel<<<CSR_BLKS, 256, 0, stream>>>(src, dst, edge_types, exc,
                                              btot, bstart, esv);
    csr3_kernel<<<NBUCK, 256, 0, stream>>>(esv, bstart, col, rowst, deg);

    const int GEMM_MBLK = (N_NODES + 63) / 64;          // 782
    const int AGG_BLKS  = (N_NODES + 15) / 16;          // 3125 (4 nodes/wave)
    const __half* Xcur = X0h;
    __half* bufs[3] = {Xb0h, Xb1h, Xb0h};
    for (int l = 0; l < NLAYERS; ++l) {
        gemm3m_kernel<<<dim3(GEMM_MBLK, 3), 256, 0, stream>>>(
            Xcur, WT + (size_t)l * 3 * DIM * DIM,
            bd + (size_t)l * DIM, bc + (size_t)l * DIM, bs + (size_t)l * DIM,
            Xdc, Xdc + NB8, Shb);
        __half* Xnext = bufs[l];
        agg_kernel<<<AGG_BLKS, 256, 0, stream>>>(rowst, deg, col, Xdc, Shb, Xnext);
        Xcur = Xnext;
    }

    const int POOL_BLKS = (N_NODES + 63) / 64;  // 782
    pool_kernel<<<POOL_BLKS, 256, 0, stream>>>(Xcur, batch_ids, sums, gcnt);
    div_kernel<<<(NGRAPHS * DIM + 255) / 256, 256, 0, stream>>>(sums, gcnt,
                                                                (float*)d_out);
}